// Round 1
// baseline (397.414 us; speedup 1.0000x reference)
//
#include <hip/hip_runtime.h>

#define NN 20000
#define NE 160000
#define NG 16
#define KP 1024          // padded feature dim
#define MTILES 157       // ceil(20000/128)
#define MPAD (MTILES*128) // 20096

typedef __attribute__((ext_vector_type(8))) short bf16x8;
typedef __attribute__((ext_vector_type(4))) float f32x4;

#define GAS __attribute__((address_space(1)))
#define LAS __attribute__((address_space(3)))

__device__ __forceinline__ unsigned short f2bf(float f) {
    unsigned int u = __float_as_uint(f);
    u += 0x7FFFu + ((u >> 16) & 1u);   // round-to-nearest-even
    return (unsigned short)(u >> 16);
}

__device__ __forceinline__ void gld_lds16(const char* g, char* l) {
    __builtin_amdgcn_global_load_lds((GAS void*)g, (LAS void*)l, 16, 0, 0);
}

// ---------------- setup kernels ----------------

__global__ void init_kernel(float* deg, int* cnt, int* cursor, int* flags,
                            float* b2p, float* wfp, const float* __restrict__ b2,
                            const float* __restrict__ wf) {
    const int i = blockIdx.x * blockDim.x + threadIdx.x;
    if (i < NN) { deg[i] = 2.0f; cnt[i] = 0; cursor[i] = 0; }   // self-loop weight 2.0
    if (i < KP) { b2p[i] = (i < 1000) ? b2[i] : 0.0f; wfp[i] = (i < 1000) ? wf[i] : 0.0f; }
    if (i < 2) flags[i] = 0;
}

// mask dtype is ambiguous (reference dtype is bool). Detect format from bit patterns
// over the first 5000 int32 words (safe to read in all three candidate layouts).
__global__ void maskdetect_kernel(const void* __restrict__ mask, int* flags) {
    const int i = blockIdx.x * blockDim.x + threadIdx.x;
    if (i >= 5000) return;
    const unsigned v = ((const unsigned*)mask)[i];
    if (v > 1u) atomicOr(&flags[0], 1);                      // not int32 {0,1}
    if (v != 0u && v != 0x3F800000u) atomicOr(&flags[1], 1); // not float32 {0,1.0f}
}

__global__ void masknorm_kernel(const void* __restrict__ mask, const int* __restrict__ flags,
                                int* __restrict__ maskN) {
    const int i = blockIdx.x * blockDim.x + threadIdx.x;
    if (i >= NN) return;
    int v;
    if (flags[0] == 0)       v = ((const int*)mask)[i] != 0;            // int32
    else if (flags[1] == 0)  v = ((const unsigned*)mask)[i] != 0u;      // float32
    else                     v = ((const unsigned char*)mask)[i] != 0;  // uint8/bool
    maskN[i] = v;
}

__global__ void deg_cnt_kernel(const int* __restrict__ ei, const float* __restrict__ ew,
                               float* deg, int* cnt) {
    const int e = blockIdx.x * blockDim.x + threadIdx.x;
    if (e >= NE) return;
    const int c = ei[NE + e];
    atomicAdd(&deg[c], ew[e]);
    atomicAdd(&cnt[c], 1);
}

__global__ void dinv_kernel(const float* __restrict__ deg, float* __restrict__ dinv) {
    const int i = blockIdx.x * blockDim.x + threadIdx.x;
    if (i >= NN) return;
    const float d = deg[i];
    dinv[i] = (d > 0.0f) ? (1.0f / sqrtf(d)) : 0.0f;
}

__global__ __launch_bounds__(1024) void scan_kernel(const int* __restrict__ cnt,
                                                    int* __restrict__ offs) {
    __shared__ int part[1024];
    const int t = threadIdx.x;
    const int base = t * 20;   // 1024*20 >= 20000
    int s = 0;
    for (int j = 0; j < 20; ++j) { const int i = base + j; if (i < NN) s += cnt[i]; }
    part[t] = s;
    __syncthreads();
    for (int off = 1; off < 1024; off <<= 1) {
        int u = (t >= off) ? part[t - off] : 0;
        __syncthreads();
        part[t] += u;
        __syncthreads();
    }
    int run = part[t] - s;   // exclusive prefix of this chunk
    for (int j = 0; j < 20; ++j) {
        const int i = base + j;
        if (i < NN) { offs[i] = run; run += cnt[i]; }
    }
}

__global__ void scatter_kernel(const int* __restrict__ ei, const float* __restrict__ ew,
                               const float* __restrict__ dinv, const int* __restrict__ offs,
                               int* cursor, int* __restrict__ ssrc, float* __restrict__ snorm) {
    const int e = blockIdx.x * blockDim.x + threadIdx.x;
    if (e >= NE) return;
    const int r = ei[e], c = ei[NE + e];
    const int pos = atomicAdd(&cursor[c], 1);
    const int idx = offs[c] + pos;
    ssrc[idx] = r;
    snorm[idx] = dinv[r] * ew[e] * dinv[c];
}

// Ax = A_norm * x  (5-wide gather; self-loop folded in)
__global__ __launch_bounds__(256) void ax_kernel(const float* __restrict__ x,
        const int* __restrict__ ssrc, const float* __restrict__ snorm,
        const int* __restrict__ offs, const int* __restrict__ cnt,
        const float* __restrict__ dinv, float* __restrict__ Ax) {
    const int i = blockIdx.x * blockDim.x + threadIdx.x;
    if (i >= NN) return;
    float a0=0,a1=0,a2=0,a3=0,a4=0;
    const int s0 = offs[i], n = cnt[i];
    for (int e = s0; e < s0 + n; ++e) {
        const int r = ssrc[e];
        const float w = snorm[e];
        const float* xr = x + r * 5;
        a0 += w*xr[0]; a1 += w*xr[1]; a2 += w*xr[2]; a3 += w*xr[3]; a4 += w*xr[4];
    }
    const float wl = 2.0f * dinv[i] * dinv[i];
    const float* xi = x + i * 5;
    a0 += wl*xi[0]; a1 += wl*xi[1]; a2 += wl*xi[2]; a3 += wl*xi[3]; a4 += wl*xi[4];
    float* o = Ax + i * 5;
    o[0]=a0; o[1]=a1; o[2]=a2; o[3]=a3; o[4]=a4;
}

// h1 = relu(Ax @ W1 + b1), written as padded bf16 [MPAD x KP]
__global__ __launch_bounds__(256) void layer1_kernel(const float* __restrict__ Ax,
        const float* __restrict__ W1, const float* __restrict__ b1,
        unsigned short* __restrict__ h1) {
    const int m = blockIdx.x;
    const int t = threadIdx.x;
    const int k = t * 4;
    if (m >= NN) {
        ushort4 zz = {0,0,0,0};
        *(ushort4*)(h1 + (size_t)m * KP + k) = zz;
        return;
    }
    __shared__ float a[5];
    if (t < 5) a[t] = Ax[m * 5 + t];
    __syncthreads();
    float r0=0,r1=0,r2=0,r3=0;
    if (k < 1000) {
        const float4 bb = *(const float4*)(b1 + k);
        r0 = bb.x; r1 = bb.y; r2 = bb.z; r3 = bb.w;
#pragma unroll
        for (int f = 0; f < 5; ++f) {
            const float4 wv = *(const float4*)(W1 + f * 1000 + k);
            const float av = a[f];
            r0 += av*wv.x; r1 += av*wv.y; r2 += av*wv.z; r3 += av*wv.w;
        }
        r0 = fmaxf(r0, 0.f); r1 = fmaxf(r1, 0.f); r2 = fmaxf(r2, 0.f); r3 = fmaxf(r3, 0.f);
    }
    ushort4 pk;
    pk.x = f2bf(r0); pk.y = f2bf(r1); pk.z = f2bf(r2); pk.w = f2bf(r3);
    *(ushort4*)(h1 + (size_t)m * KP + k) = pk;
}

// W2t[n][k] = bf16(W2[k][n]), zero-padded to 1024x1024
__global__ void w2t_kernel(const float* __restrict__ W2, unsigned short* __restrict__ W2t) {
    __shared__ float tile[32][33];
    const int n0 = blockIdx.x * 32;
    const int k0 = blockIdx.y * 32;
    const int tx = threadIdx.x;  // 0..31
    const int ty = threadIdx.y;  // 0..7
#pragma unroll
    for (int j = 0; j < 4; ++j) {
        const int k = k0 + ty + j * 8;
        const int n = n0 + tx;
        tile[ty + j * 8][tx] = (k < 1000 && n < 1000) ? W2[k * 1000 + n] : 0.0f;
    }
    __syncthreads();
#pragma unroll
    for (int j = 0; j < 4; ++j) {
        const int n = n0 + ty + j * 8;
        const int k = k0 + tx;
        W2t[(size_t)n * KP + k] = f2bf(tile[tx][ty + j * 8]);
    }
}

// Z = h1 @ W2   (bf16 MFMA 16x16x32, 128x128 tile, BK=32, global_load_lds staging,
//  XOR-swizzled k-chunks so ds_read_b128 frag loads are 2-way/free on LDS banks)
__global__ __launch_bounds__(256) void gemm_kernel(const unsigned short* __restrict__ A,
                                                   const unsigned short* __restrict__ B,
                                                   float* __restrict__ Z) {
    __shared__ unsigned short As[4096];  // 128 rows x 32 k (bf16) = 8 KB
    __shared__ unsigned short Bs[4096];
    const int tid = threadIdx.x;
    const int lane = tid & 63;
    const int wv = tid >> 6;
    const int tm = blockIdx.x, tn = blockIdx.y;
    const int wr = wv >> 1, wc = wv & 1;

    // staging: lane handles 16B chunk; global chunk is XOR-swizzled by row pair
    const int chunk = ((tid & 3) ^ ((tid >> 3) & 3)) * 16;
    const int rsub = tid >> 2;   // row 0..63 (+64 in round 1)
    const char* Ag = (const char*)(A + (size_t)(tm * 128 + rsub) * KP) + chunk;
    const char* Bg = (const char*)(B + (size_t)(tn * 128 + rsub) * KP) + chunk;
    char* AsW = (char*)As + wv * 1024;
    char* BsW = (char*)Bs + wv * 1024;

    f32x4 acc[4][4];
#pragma unroll
    for (int i = 0; i < 4; ++i)
#pragma unroll
        for (int j = 0; j < 4; ++j) acc[i][j] = (f32x4){0.f, 0.f, 0.f, 0.f};

    const int m = lane & 15;
    const int quad = lane >> 4;
    const int sw = quad ^ ((m >> 1) & 3);       // swizzled k-chunk slot
    const int aoff = (wr * 64 + m) * 64 + sw * 16;  // byte offset, mt stride = 1024B
    const int boff = (wc * 64 + m) * 64 + sw * 16;

    for (int kk = 0; kk < KP; kk += 32) {
        __syncthreads();
        const int kb = kk * 2;
        gld_lds16(Ag + kb,             AsW);
        gld_lds16(Ag + kb + 64 * 2048, AsW + 4096);
        gld_lds16(Bg + kb,             BsW);
        gld_lds16(Bg + kb + 64 * 2048, BsW + 4096);
        __syncthreads();
        bf16x8 af[4], bfv[4];
#pragma unroll
        for (int mt = 0; mt < 4; ++mt)
            af[mt] = *(const bf16x8*)((const char*)As + aoff + mt * 1024);
#pragma unroll
        for (int nt = 0; nt < 4; ++nt)
            bfv[nt] = *(const bf16x8*)((const char*)Bs + boff + nt * 1024);
#pragma unroll
        for (int mt = 0; mt < 4; ++mt)
#pragma unroll
            for (int nt = 0; nt < 4; ++nt)
                acc[mt][nt] = __builtin_amdgcn_mfma_f32_16x16x32_bf16(af[mt], bfv[nt], acc[mt][nt], 0, 0, 0);
    }

    // C/D layout: col = lane&15, row = quad*4 + reg
    const int col0 = tn * 128 + wc * 64 + (lane & 15);
    const int row00 = tm * 128 + wr * 64 + quad * 4;
#pragma unroll
    for (int mt = 0; mt < 4; ++mt)
#pragma unroll
        for (int nt = 0; nt < 4; ++nt) {
            float* zp = Z + (size_t)(row00 + mt * 16) * KP + col0 + nt * 16;
#pragma unroll
            for (int r = 0; r < 4; ++r) zp[(size_t)r * KP] = acc[mt][nt][r];
        }
}

// logits[i] = relu(A_norm*Z + b2) . Wf + bf   (h2 never materialized)
__global__ __launch_bounds__(256) void agg2_kernel(const float* __restrict__ Z,
        const int* __restrict__ ssrc, const float* __restrict__ snorm,
        const int* __restrict__ offs, const int* __restrict__ cnt,
        const float* __restrict__ dinv, const float* __restrict__ b2p,
        const float* __restrict__ wfp, const float* __restrict__ bf_,
        float* __restrict__ logits) {
    const int i = blockIdx.x;
    const int t = threadIdx.x;
    const float4* Z4 = (const float4*)Z;
    float4 acc = {0.f, 0.f, 0.f, 0.f};
    const int s0 = offs[i], n = cnt[i];
    for (int e = s0; e < s0 + n; ++e) {
        const int r = ssrc[e];
        const float w = snorm[e];
        const float4 z = Z4[(size_t)r * 256 + t];
        acc.x += w * z.x; acc.y += w * z.y; acc.z += w * z.z; acc.w += w * z.w;
    }
    {
        const float wl = 2.0f * dinv[i] * dinv[i];
        const float4 z = Z4[(size_t)i * 256 + t];
        acc.x += wl * z.x; acc.y += wl * z.y; acc.z += wl * z.z; acc.w += wl * z.w;
    }
    const float4 b = ((const float4*)b2p)[t];
    const float4 wf = ((const float4*)wfp)[t];
    float p = fmaxf(acc.x + b.x, 0.f) * wf.x + fmaxf(acc.y + b.y, 0.f) * wf.y
            + fmaxf(acc.z + b.z, 0.f) * wf.z + fmaxf(acc.w + b.w, 0.f) * wf.w;
    for (int off = 32; off; off >>= 1) p += __shfl_down(p, off);
    __shared__ float red[4];
    if ((t & 63) == 0) red[t >> 6] = p;
    __syncthreads();
    if (t == 0) logits[i] = red[0] + red[1] + red[2] + red[3] + bf_[0];
}

__global__ __launch_bounds__(256) void softmax_kernel(const float* __restrict__ logits,
        const int* __restrict__ maskN, const int* __restrict__ batch,
        float* __restrict__ out) {
    const int g = blockIdx.x;
    const int t = threadIdx.x;
    __shared__ float red[4];
    __shared__ float sval;
    float mx = -1e30f;
    for (int i = t; i < NN; i += 256)
        if (batch[i] == g && maskN[i]) mx = fmaxf(mx, logits[i]);
    for (int off = 32; off; off >>= 1) mx = fmaxf(mx, __shfl_down(mx, off));
    if ((t & 63) == 0) red[t >> 6] = mx;
    __syncthreads();
    if (t == 0) sval = fmaxf(fmaxf(red[0], red[1]), fmaxf(red[2], red[3]));
    __syncthreads();
    mx = sval;
    __syncthreads();
    float sm = 0.f;
    for (int i = t; i < NN; i += 256)
        if (batch[i] == g && maskN[i]) sm += expf(logits[i] - mx);
    for (int off = 32; off; off >>= 1) sm += __shfl_down(sm, off);
    if ((t & 63) == 0) red[t >> 6] = sm;
    __syncthreads();
    if (t == 0) sval = red[0] + red[1] + red[2] + red[3];
    __syncthreads();
    const float inv = 1.0f / fmaxf(sval, 1e-16f);
    for (int i = t; i < NN; i += 256)
        if (batch[i] == g) out[i] = maskN[i] ? expf(logits[i] - mx) * inv : 0.0f;
}

extern "C" void kernel_launch(void* const* d_in, const int* in_sizes, int n_in,
                              void* d_out, int out_size, void* d_ws, size_t ws_size,
                              hipStream_t stream) {
    (void)in_sizes; (void)n_in; (void)out_size; (void)ws_size;
    const float* x   = (const float*)d_in[0];
    const float* ew  = (const float*)d_in[1];
    const float* W1  = (const float*)d_in[2];
    const float* b1  = (const float*)d_in[3];
    const float* W2  = (const float*)d_in[4];
    const float* b2  = (const float*)d_in[5];
    const float* Wf  = (const float*)d_in[6];
    const float* bfp = (const float*)d_in[7];
    const int*   ei  = (const int*)d_in[8];
    const void*  mask  = d_in[9];
    const int*   batch = (const int*)d_in[10];
    float* out = (float*)d_out;

    char* p = (char*)d_ws;
    auto carve = [&](size_t bytes) { char* q = p; p += (bytes + 255) & ~(size_t)255; return q; };
    float* deg    = (float*)carve(NN * 4);
    float* dinv   = (float*)carve(NN * 4);
    int*   cnt    = (int*)carve(NN * 4);
    int*   offs   = (int*)carve(NN * 4);
    int*   cursor = (int*)carve(NN * 4);
    int*   flags  = (int*)carve(256);
    int*   maskN  = (int*)carve(NN * 4);
    int*   ssrc   = (int*)carve(NE * 4);
    float* snorm  = (float*)carve(NE * 4);
    float* Ax     = (float*)carve(NN * 5 * 4);
    float* b2p    = (float*)carve(KP * 4);
    float* wfp    = (float*)carve(KP * 4);
    float* logits = (float*)carve(NN * 4);
    unsigned short* W2t = (unsigned short*)carve((size_t)KP * KP * 2);
    unsigned short* h1  = (unsigned short*)carve((size_t)MPAD * KP * 2);
    float* Z      = (float*)carve((size_t)MPAD * KP * 4);   // total ~128 MB

    hipLaunchKernelGGL(init_kernel,     dim3(79),  dim3(256), 0, stream, deg, cnt, cursor, flags, b2p, wfp, b2, Wf);
    hipLaunchKernelGGL(maskdetect_kernel, dim3(20), dim3(256), 0, stream, mask, flags);
    hipLaunchKernelGGL(masknorm_kernel, dim3(79),  dim3(256), 0, stream, mask, flags, maskN);
    hipLaunchKernelGGL(deg_cnt_kernel,  dim3(625), dim3(256), 0, stream, ei, ew, deg, cnt);
    hipLaunchKernelGGL(dinv_kernel,     dim3(79),  dim3(256), 0, stream, deg, dinv);
    hipLaunchKernelGGL(scan_kernel,     dim3(1),   dim3(1024), 0, stream, cnt, offs);
    hipLaunchKernelGGL(scatter_kernel,  dim3(625), dim3(256), 0, stream, ei, ew, dinv, offs, cursor, ssrc, snorm);
    hipLaunchKernelGGL(ax_kernel,       dim3(79),  dim3(256), 0, stream, x, ssrc, snorm, offs, cnt, dinv, Ax);
    hipLaunchKernelGGL(layer1_kernel,   dim3(MPAD), dim3(256), 0, stream, Ax, W1, b1, h1);
    hipLaunchKernelGGL(w2t_kernel,      dim3(32, 32), dim3(32, 8), 0, stream, W2, W2t);
    hipLaunchKernelGGL(gemm_kernel,     dim3(MTILES, 8), dim3(256), 0, stream, h1, W2t, Z);
    hipLaunchKernelGGL(agg2_kernel,     dim3(NN),  dim3(256), 0, stream, Z, ssrc, snorm, offs, cnt, dinv, b2p, wfp, bfp, logits);
    hipLaunchKernelGGL(softmax_kernel,  dim3(NG),  dim3(256), 0, stream, logits, maskN, batch, out);
}

// Round 2
// 305.451 us; speedup vs baseline: 1.3011x; 1.3011x over previous
//
#include <hip/hip_runtime.h>

#define NN 20000
#define NE 160000
#define NG 16
#define KP 1024          // padded feature dim
#define MTILES 157       // ceil(20000/128)
#define MPAD (MTILES*128) // 20096

typedef __attribute__((ext_vector_type(8))) short bf16x8;
typedef __attribute__((ext_vector_type(4))) float f32x4;

#define GAS __attribute__((address_space(1)))
#define LAS __attribute__((address_space(3)))

__device__ __forceinline__ unsigned short f2bf(float f) {
    unsigned int u = __float_as_uint(f);
    u += 0x7FFFu + ((u >> 16) & 1u);   // round-to-nearest-even
    return (unsigned short)(u >> 16);
}

__device__ __forceinline__ float bf2f(unsigned short u) {
    return __uint_as_float(((unsigned)u) << 16);
}

__device__ __forceinline__ void gld_lds16(const char* g, char* l) {
    __builtin_amdgcn_global_load_lds((GAS void*)g, (LAS void*)l, 16, 0, 0);
}

// ---------------- setup kernels ----------------

__global__ void init_kernel(float* deg, int* cnt, int* cursor, int* flags,
                            float* b2p, float* wfp, float* logits,
                            const float* __restrict__ b2, const float* __restrict__ wf) {
    const int i = blockIdx.x * blockDim.x + threadIdx.x;
    if (i < NN) { deg[i] = 2.0f; cnt[i] = 0; cursor[i] = 0; logits[i] = 0.0f; }
    if (i < KP) { b2p[i] = (i < 1000) ? b2[i] : 0.0f; wfp[i] = (i < 1000) ? wf[i] : 0.0f; }
    if (i < 2) flags[i] = 0;
}

// mask dtype is ambiguous (reference dtype is bool). Detect format from bit patterns
// over the first 5000 int32 words (safe to read in all three candidate layouts).
__global__ void maskdetect_kernel(const void* __restrict__ mask, int* flags) {
    const int i = blockIdx.x * blockDim.x + threadIdx.x;
    if (i >= 5000) return;
    const unsigned v = ((const unsigned*)mask)[i];
    if (v > 1u) atomicOr(&flags[0], 1);                      // not int32 {0,1}
    if (v != 0u && v != 0x3F800000u) atomicOr(&flags[1], 1); // not float32 {0,1.0f}
}

__global__ void deg_cnt_kernel(const int* __restrict__ ei, const float* __restrict__ ew,
                               float* deg, int* cnt) {
    const int e = blockIdx.x * blockDim.x + threadIdx.x;
    if (e >= NE) return;
    const int c = ei[NE + e];
    atomicAdd(&deg[c], ew[e]);
    atomicAdd(&cnt[c], 1);
}

__global__ void dinv_kernel(const float* __restrict__ deg, float* __restrict__ dinv) {
    const int i = blockIdx.x * blockDim.x + threadIdx.x;
    if (i >= NN) return;
    const float d = deg[i];
    dinv[i] = (d > 0.0f) ? (1.0f / sqrtf(d)) : 0.0f;
}

__global__ __launch_bounds__(1024) void scan_kernel(const int* __restrict__ cnt,
                                                    int* __restrict__ offs) {
    __shared__ int part[1024];
    const int t = threadIdx.x;
    const int base = t * 20;   // 1024*20 >= 20000
    int s = 0;
    for (int j = 0; j < 20; ++j) { const int i = base + j; if (i < NN) s += cnt[i]; }
    part[t] = s;
    __syncthreads();
    for (int off = 1; off < 1024; off <<= 1) {
        int u = (t >= off) ? part[t - off] : 0;
        __syncthreads();
        part[t] += u;
        __syncthreads();
    }
    int run = part[t] - s;   // exclusive prefix of this chunk
    for (int j = 0; j < 20; ++j) {
        const int i = base + j;
        if (i < NN) { offs[i] = run; run += cnt[i]; }
    }
}

__global__ void scatter_kernel(const int* __restrict__ ei, const float* __restrict__ ew,
                               const float* __restrict__ dinv, const int* __restrict__ offs,
                               int* cursor, int* __restrict__ ssrc, float* __restrict__ snorm) {
    const int e = blockIdx.x * blockDim.x + threadIdx.x;
    if (e >= NE) return;
    const int r = ei[e], c = ei[NE + e];
    const int pos = atomicAdd(&cursor[c], 1);
    const int idx = offs[c] + pos;
    ssrc[idx] = r;
    snorm[idx] = dinv[r] * ew[e] * dinv[c];
}

// Ax = A_norm * x  (5-wide gather; self-loop folded in)
__global__ __launch_bounds__(256) void ax_kernel(const float* __restrict__ x,
        const int* __restrict__ ssrc, const float* __restrict__ snorm,
        const int* __restrict__ offs, const int* __restrict__ cnt,
        const float* __restrict__ dinv, float* __restrict__ Ax) {
    const int i = blockIdx.x * blockDim.x + threadIdx.x;
    if (i >= NN) return;
    float a0=0,a1=0,a2=0,a3=0,a4=0;
    const int s0 = offs[i], n = cnt[i];
    for (int e = s0; e < s0 + n; ++e) {
        const int r = ssrc[e];
        const float w = snorm[e];
        const float* xr = x + r * 5;
        a0 += w*xr[0]; a1 += w*xr[1]; a2 += w*xr[2]; a3 += w*xr[3]; a4 += w*xr[4];
    }
    const float wl = 2.0f * dinv[i] * dinv[i];
    const float* xi = x + i * 5;
    a0 += wl*xi[0]; a1 += wl*xi[1]; a2 += wl*xi[2]; a3 += wl*xi[3]; a4 += wl*xi[4];
    float* o = Ax + i * 5;
    o[0]=a0; o[1]=a1; o[2]=a2; o[3]=a3; o[4]=a4;
}

// h1 = relu(Ax @ W1 + b1), written as padded bf16 [MPAD x KP]
__global__ __launch_bounds__(256) void layer1_kernel(const float* __restrict__ Ax,
        const float* __restrict__ W1, const float* __restrict__ b1,
        unsigned short* __restrict__ h1) {
    const int m = blockIdx.x;
    const int t = threadIdx.x;
    const int k = t * 4;
    if (m >= NN) {
        ushort4 zz = {0,0,0,0};
        *(ushort4*)(h1 + (size_t)m * KP + k) = zz;
        return;
    }
    __shared__ float a[5];
    if (t < 5) a[t] = Ax[m * 5 + t];
    __syncthreads();
    float r0=0,r1=0,r2=0,r3=0;
    if (k < 1000) {
        const float4 bb = *(const float4*)(b1 + k);
        r0 = bb.x; r1 = bb.y; r2 = bb.z; r3 = bb.w;
#pragma unroll
        for (int f = 0; f < 5; ++f) {
            const float4 wv = *(const float4*)(W1 + f * 1000 + k);
            const float av = a[f];
            r0 += av*wv.x; r1 += av*wv.y; r2 += av*wv.z; r3 += av*wv.w;
        }
        r0 = fmaxf(r0, 0.f); r1 = fmaxf(r1, 0.f); r2 = fmaxf(r2, 0.f); r3 = fmaxf(r3, 0.f);
    }
    ushort4 pk;
    pk.x = f2bf(r0); pk.y = f2bf(r1); pk.z = f2bf(r2); pk.w = f2bf(r3);
    *(ushort4*)(h1 + (size_t)m * KP + k) = pk;
}

// W2t[n][k] = bf16(W2[k][n]), zero-padded to 1024x1024
__global__ void w2t_kernel(const float* __restrict__ W2, unsigned short* __restrict__ W2t) {
    __shared__ float tile[32][33];
    const int n0 = blockIdx.x * 32;
    const int k0 = blockIdx.y * 32;
    const int tx = threadIdx.x;  // 0..31
    const int ty = threadIdx.y;  // 0..7
#pragma unroll
    for (int j = 0; j < 4; ++j) {
        const int k = k0 + ty + j * 8;
        const int n = n0 + tx;
        tile[ty + j * 8][tx] = (k < 1000 && n < 1000) ? W2[k * 1000 + n] : 0.0f;
    }
    __syncthreads();
#pragma unroll
    for (int j = 0; j < 4; ++j) {
        const int n = n0 + ty + j * 8;
        const int k = k0 + tx;
        W2t[(size_t)n * KP + k] = f2bf(tile[tx][ty + j * 8]);
    }
}

// G = A_norm * h1  (1024-wide gather on bf16 rows; 2 edges in flight per block,
//  fp32 accumulate, bf16 out). Pad rows [NN, MPAD) written as zeros.
__global__ __launch_bounds__(256) void agg1k_kernel(const unsigned short* __restrict__ h1,
        const int* __restrict__ ssrc, const float* __restrict__ snorm,
        const int* __restrict__ offs, const int* __restrict__ cnt,
        const float* __restrict__ dinv, unsigned short* __restrict__ G) {
    const int i = blockIdx.x;
    const int t = threadIdx.x;
    const int sub = t >> 7;          // 0/1: which edge of the pair
    const int tc = t & 127;          // col group: cols [tc*8, tc*8+8)
    unsigned short* grow = G + (size_t)i * KP + tc * 8;
    if (i >= NN) {
        if (sub == 0) {
            bf16x8 z = {0,0,0,0,0,0,0,0};
            *(bf16x8*)grow = z;
        }
        return;
    }
    float acc[8] = {0,0,0,0,0,0,0,0};
    const int s0 = offs[i], n = cnt[i];
    for (int e = s0 + sub; e < s0 + n; e += 2) {
        const int r = ssrc[e];
        const float w = snorm[e];
        const bf16x8 hv = *(const bf16x8*)(h1 + (size_t)r * KP + tc * 8);
#pragma unroll
        for (int j = 0; j < 8; ++j) acc[j] += w * bf2f((unsigned short)hv[j]);
    }
    if (sub == 0) {
        const float wl = 2.0f * dinv[i] * dinv[i];
        const bf16x8 hv = *(const bf16x8*)(h1 + (size_t)i * KP + tc * 8);
#pragma unroll
        for (int j = 0; j < 8; ++j) acc[j] += wl * bf2f((unsigned short)hv[j]);
    }
    __shared__ float red[128][8];
    if (sub == 1) {
#pragma unroll
        for (int j = 0; j < 8; ++j) red[tc][j] = acc[j];
    }
    __syncthreads();
    if (sub == 0) {
        bf16x8 o;
#pragma unroll
        for (int j = 0; j < 8; ++j) o[j] = (short)f2bf(acc[j] + red[tc][j]);
        *(bf16x8*)grow = o;
    }
}

// logits += sum_cols relu(G @ W2 + b2) * Wf   — fused epilogue, Z never materialized.
// bf16 MFMA 16x16x32, 128x128 tile, BK=32, global_load_lds staging, XOR-swizzled LDS.
__global__ __launch_bounds__(256) void gemm_kernel(const unsigned short* __restrict__ A,
                                                   const unsigned short* __restrict__ B,
                                                   const float* __restrict__ b2p,
                                                   const float* __restrict__ wfp,
                                                   float* __restrict__ logits) {
    __shared__ unsigned short As[4096];  // 128 rows x 32 k (bf16) = 8 KB
    __shared__ unsigned short Bs[4096];
    const int tid = threadIdx.x;
    const int lane = tid & 63;
    const int wv = tid >> 6;
    const int tm = blockIdx.x, tn = blockIdx.y;
    const int wr = wv >> 1, wc = wv & 1;

    // staging: lane handles 16B chunk; global chunk is XOR-swizzled by row pair
    const int chunk = ((tid & 3) ^ ((tid >> 3) & 3)) * 16;
    const int rsub = tid >> 2;   // row 0..63 (+64 in round 1)
    const char* Ag = (const char*)(A + (size_t)(tm * 128 + rsub) * KP) + chunk;
    const char* Bg = (const char*)(B + (size_t)(tn * 128 + rsub) * KP) + chunk;
    char* AsW = (char*)As + wv * 1024;
    char* BsW = (char*)Bs + wv * 1024;

    f32x4 acc[4][4];
#pragma unroll
    for (int i = 0; i < 4; ++i)
#pragma unroll
        for (int j = 0; j < 4; ++j) acc[i][j] = (f32x4){0.f, 0.f, 0.f, 0.f};

    const int m = lane & 15;
    const int quad = lane >> 4;
    const int sw = quad ^ ((m >> 1) & 3);       // swizzled k-chunk slot
    const int aoff = (wr * 64 + m) * 64 + sw * 16;  // byte offset, mt stride = 1024B
    const int boff = (wc * 64 + m) * 64 + sw * 16;

    for (int kk = 0; kk < KP; kk += 32) {
        __syncthreads();
        const int kb = kk * 2;
        gld_lds16(Ag + kb,             AsW);
        gld_lds16(Ag + kb + 64 * 2048, AsW + 4096);
        gld_lds16(Bg + kb,             BsW);
        gld_lds16(Bg + kb + 64 * 2048, BsW + 4096);
        __syncthreads();
        bf16x8 af[4], bfv[4];
#pragma unroll
        for (int mt = 0; mt < 4; ++mt)
            af[mt] = *(const bf16x8*)((const char*)As + aoff + mt * 1024);
#pragma unroll
        for (int nt = 0; nt < 4; ++nt)
            bfv[nt] = *(const bf16x8*)((const char*)Bs + boff + nt * 1024);
#pragma unroll
        for (int mt = 0; mt < 4; ++mt)
#pragma unroll
            for (int nt = 0; nt < 4; ++nt)
                acc[mt][nt] = __builtin_amdgcn_mfma_f32_16x16x32_bf16(af[mt], bfv[nt], acc[mt][nt], 0, 0, 0);
    }

    // C/D layout: col = lane&15, row = quad*4 + reg.
    // Epilogue: p(row) = sum_col relu(h2[row][col]+b2[col])*wf[col]; butterfly over
    // the 16 col-lanes, then one atomicAdd per (row).
    const int col0 = tn * 128 + wc * 64 + m;
    const int row00 = tm * 128 + wr * 64 + quad * 4;
#pragma unroll
    for (int mt = 0; mt < 4; ++mt) {
        float ps0 = 0.f, ps1 = 0.f, ps2 = 0.f, ps3 = 0.f;
#pragma unroll
        for (int nt = 0; nt < 4; ++nt) {
            const int c = col0 + nt * 16;
            const float bb = b2p[c];
            const float wf = wfp[c];
            ps0 += fmaxf(acc[mt][nt][0] + bb, 0.f) * wf;
            ps1 += fmaxf(acc[mt][nt][1] + bb, 0.f) * wf;
            ps2 += fmaxf(acc[mt][nt][2] + bb, 0.f) * wf;
            ps3 += fmaxf(acc[mt][nt][3] + bb, 0.f) * wf;
        }
#pragma unroll
        for (int msk = 1; msk < 16; msk <<= 1) {
            ps0 += __shfl_xor(ps0, msk);
            ps1 += __shfl_xor(ps1, msk);
            ps2 += __shfl_xor(ps2, msk);
            ps3 += __shfl_xor(ps3, msk);
        }
        if (m == 0) {
            const int row = row00 + mt * 16;
            if (row + 0 < NN) atomicAdd(&logits[row + 0], ps0);
            if (row + 1 < NN) atomicAdd(&logits[row + 1], ps1);
            if (row + 2 < NN) atomicAdd(&logits[row + 2], ps2);
            if (row + 3 < NN) atomicAdd(&logits[row + 3], ps3);
        }
    }
}

// masked segment softmax; batch is sorted so each graph is a contiguous range
// found by binary search. bf bias dropped (uniform shift cancels in softmax).
__global__ __launch_bounds__(256) void softmax_kernel(const float* __restrict__ logits,
        const void* __restrict__ mask, const int* __restrict__ flags,
        const int* __restrict__ batch, float* __restrict__ out) {
    const int g = blockIdx.x;
    const int t = threadIdx.x;
    __shared__ int s_lo, s_hi;
    __shared__ float red[4];
    __shared__ float sval;
    if (t == 0) {
        int lo = 0, hi = NN;
        while (lo < hi) { const int mid = (lo + hi) >> 1; if (batch[mid] < g) lo = mid + 1; else hi = mid; }
        s_lo = lo;
        int lo2 = lo, hi2 = NN;
        while (lo2 < hi2) { const int mid = (lo2 + hi2) >> 1; if (batch[mid] < g + 1) lo2 = mid + 1; else hi2 = mid; }
        s_hi = lo2;
    }
    __syncthreads();
    const int lo = s_lo, hi = s_hi;
    const int f0 = flags[0], f1 = flags[1];
    auto mget = [&](int i) -> int {
        if (f0 == 0) return ((const int*)mask)[i] != 0;
        if (f1 == 0) return ((const unsigned*)mask)[i] != 0u;
        return ((const unsigned char*)mask)[i] != 0;
    };
    float mx = -1e30f;
    for (int i = lo + t; i < hi; i += 256)
        if (mget(i)) mx = fmaxf(mx, logits[i]);
    for (int off = 32; off; off >>= 1) mx = fmaxf(mx, __shfl_down(mx, off));
    if ((t & 63) == 0) red[t >> 6] = mx;
    __syncthreads();
    if (t == 0) sval = fmaxf(fmaxf(red[0], red[1]), fmaxf(red[2], red[3]));
    __syncthreads();
    mx = sval;
    __syncthreads();
    float sm = 0.f;
    for (int i = lo + t; i < hi; i += 256)
        if (mget(i)) sm += expf(logits[i] - mx);
    for (int off = 32; off; off >>= 1) sm += __shfl_down(sm, off);
    if ((t & 63) == 0) red[t >> 6] = sm;
    __syncthreads();
    if (t == 0) sval = red[0] + red[1] + red[2] + red[3];
    __syncthreads();
    const float inv = 1.0f / fmaxf(sval, 1e-16f);
    for (int i = lo + t; i < hi; i += 256)
        out[i] = mget(i) ? expf(logits[i] - mx) * inv : 0.0f;
}

extern "C" void kernel_launch(void* const* d_in, const int* in_sizes, int n_in,
                              void* d_out, int out_size, void* d_ws, size_t ws_size,
                              hipStream_t stream) {
    (void)in_sizes; (void)n_in; (void)out_size; (void)ws_size;
    const float* x   = (const float*)d_in[0];
    const float* ew  = (const float*)d_in[1];
    const float* W1  = (const float*)d_in[2];
    const float* b1  = (const float*)d_in[3];
    const float* W2  = (const float*)d_in[4];
    const float* b2  = (const float*)d_in[5];
    const float* Wf  = (const float*)d_in[6];
    const int*   ei  = (const int*)d_in[8];
    const void*  mask  = d_in[9];
    const int*   batch = (const int*)d_in[10];
    float* out = (float*)d_out;

    char* p = (char*)d_ws;
    auto carve = [&](size_t bytes) { char* q = p; p += (bytes + 255) & ~(size_t)255; return q; };
    float* deg    = (float*)carve(NN * 4);
    float* dinv   = (float*)carve(NN * 4);
    int*   cnt    = (int*)carve(NN * 4);
    int*   offs   = (int*)carve(NN * 4);
    int*   cursor = (int*)carve(NN * 4);
    int*   flags  = (int*)carve(256);
    int*   ssrc   = (int*)carve(NE * 4);
    float* snorm  = (float*)carve(NE * 4);
    float* Ax     = (float*)carve(NN * 5 * 4);
    float* b2p    = (float*)carve(KP * 4);
    float* wfp    = (float*)carve(KP * 4);
    float* logits = (float*)carve(NN * 4);
    unsigned short* W2t = (unsigned short*)carve((size_t)KP * KP * 2);
    unsigned short* h1  = (unsigned short*)carve((size_t)MPAD * KP * 2);
    unsigned short* G   = (unsigned short*)carve((size_t)MPAD * KP * 2);

    hipLaunchKernelGGL(init_kernel,       dim3(79),  dim3(256), 0, stream, deg, cnt, cursor, flags, b2p, wfp, logits, b2, Wf);
    hipLaunchKernelGGL(maskdetect_kernel, dim3(20),  dim3(256), 0, stream, mask, flags);
    hipLaunchKernelGGL(deg_cnt_kernel,    dim3(625), dim3(256), 0, stream, ei, ew, deg, cnt);
    hipLaunchKernelGGL(dinv_kernel,       dim3(79),  dim3(256), 0, stream, deg, dinv);
    hipLaunchKernelGGL(scan_kernel,       dim3(1),   dim3(1024), 0, stream, cnt, offs);
    hipLaunchKernelGGL(scatter_kernel,    dim3(625), dim3(256), 0, stream, ei, ew, dinv, offs, cursor, ssrc, snorm);
    hipLaunchKernelGGL(ax_kernel,         dim3(79),  dim3(256), 0, stream, x, ssrc, snorm, offs, cnt, dinv, Ax);
    hipLaunchKernelGGL(layer1_kernel,     dim3(MPAD), dim3(256), 0, stream, Ax, W1, b1, h1);
    hipLaunchKernelGGL(w2t_kernel,        dim3(32, 32), dim3(32, 8), 0, stream, W2, W2t);
    hipLaunchKernelGGL(agg1k_kernel,      dim3(MPAD), dim3(256), 0, stream, h1, ssrc, snorm, offs, cnt, dinv, G);
    hipLaunchKernelGGL(gemm_kernel,       dim3(MTILES, 8), dim3(256), 0, stream, G, W2t, b2p, wfp, logits);
    hipLaunchKernelGGL(softmax_kernel,    dim3(NG),  dim3(256), 0, stream, logits, mask, flags, batch, out);
}